// Round 1
// baseline (370.058 us; speedup 1.0000x reference)
//
#include <hip/hip_runtime.h>

// SLAM layer, fused: h = relu(x_aux@W1+b1); S = h@W2+b2; out[t] = x_main[-1,t,0] @ S[:,t,:]
// N,T,M,A,D = 4,1024,128,64,128. One block per t; bf16 MFMA 16x16x32 with fp32 accum.

#define TT 1024
#define MM 128
#define AA 64
#define DD 128

typedef float  f32x4  __attribute__((ext_vector_type(4)));
typedef __bf16 bf16x8 __attribute__((ext_vector_type(8)));
typedef __bf16 bf16x4 __attribute__((ext_vector_type(4)));

// LDS row strides (in elements): 64-wide mats padded to 72 (144 B = 9 granules, odd -> 2-way max),
// 128-wide mats padded to 136 (272 B = 17 granules, odd -> 2-way max). All frag reads 16 B aligned.

__global__ __launch_bounds__(512, 1)
void slam_fused(const float* __restrict__ xm, const float* __restrict__ xa,
                const float* __restrict__ W1, const float* __restrict__ b1,
                const float* __restrict__ W2, const float* __restrict__ b2,
                float* __restrict__ out)
{
    __shared__ __bf16 ldsR1[18432];   // phase 0/1: Xa[128][72] @0 | W1T[128][72] @9216 ; phase 2+: ST[128][136]
    __shared__ __bf16 ldsH [17408];   // h[128][136]   (row = m, col = d)
    __shared__ __bf16 ldsW2[17408];   // W2T[128][136] (row = k, col = d)
    __shared__ float  ldsB1[128];
    __shared__ float  ldsB2[128];

    const int t    = blockIdx.x;
    const int tid  = threadIdx.x;
    const int lane = tid & 63;
    const int wv   = tid >> 6;       // 0..7
    const int n    = lane & 15;      // MFMA col / A-row-in-tile index
    const int q    = lane >> 4;      // quad 0..3

    __bf16* Xal  = ldsR1;            // stride 72
    __bf16* W1Tl = ldsR1 + 9216;     // stride 72
    __bf16* Sl   = ldsR1;            // stride 136 (alias; live only after phase 2 barrier)

    // ---- prefetch A operand of phase 3: main_last[t] rows, fp32 (converted later) ----
    const float* arow = xm + (size_t)3 * TT * MM * MM + ((size_t)t * MM + wv * 16 + n) * MM;
    f32x4 apre[8];
#pragma unroll
    for (int ks = 0; ks < 4; ++ks) {
        apre[2 * ks]     = *(const f32x4*)(arow + ks * 32 + q * 8);
        apre[2 * ks + 1] = *(const f32x4*)(arow + ks * 32 + q * 8 + 4);
    }

    // ---- stage Xa: x_aux[m, t, :] -> Xal[m][a] (bf16) ----
#pragma unroll
    for (int p = 0; p < 4; ++p) {
        int m = p * 32 + (tid >> 4);
        int c = (tid & 15) * 4;
        f32x4 v = *(const f32x4*)(xa + ((size_t)m * TT + t) * AA + c);
        bf16x4 pk;
        pk[0] = (__bf16)v[0]; pk[1] = (__bf16)v[1]; pk[2] = (__bf16)v[2]; pk[3] = (__bf16)v[3];
        *(bf16x4*)(Xal + m * 72 + c) = pk;
    }
    // ---- stage W1T: W1[a][d] -> W1Tl[d][a] ----
#pragma unroll
    for (int p = 0; p < 4; ++p) {
        int idx = p * 512 + tid;
        int a = idx >> 5;
        int d = (idx & 31) * 4;
        f32x4 v = *(const f32x4*)(W1 + a * DD + d);
        W1Tl[(d + 0) * 72 + a] = (__bf16)v[0];
        W1Tl[(d + 1) * 72 + a] = (__bf16)v[1];
        W1Tl[(d + 2) * 72 + a] = (__bf16)v[2];
        W1Tl[(d + 3) * 72 + a] = (__bf16)v[3];
    }
    // ---- stage W2T: W2[d][k] -> ldsW2[k][d] ----
#pragma unroll
    for (int p = 0; p < 8; ++p) {
        int idx = p * 512 + tid;
        int d = idx >> 5;
        int k = (idx & 31) * 4;
        f32x4 v = *(const f32x4*)(W2 + d * DD + k);
        ldsW2[(k + 0) * 136 + d] = (__bf16)v[0];
        ldsW2[(k + 1) * 136 + d] = (__bf16)v[1];
        ldsW2[(k + 2) * 136 + d] = (__bf16)v[2];
        ldsW2[(k + 3) * 136 + d] = (__bf16)v[3];
    }
    if (tid < 128)      ldsB1[tid] = b1[tid];
    else if (tid < 256) ldsB2[tid - 128] = b2[tid - 128];

    __syncthreads();

    f32x4 acc[8];

    // ---- phase 1: hT-oriented: D[d][m] = sum_a W1T[d][a] * Xa[m][a]  (wave wv owns d-band wv*16..+15) ----
    {
        bf16x8 a1[2];
#pragma unroll
        for (int ks = 0; ks < 2; ++ks)
            a1[ks] = *(const bf16x8*)(W1Tl + (wv * 16 + n) * 72 + ks * 32 + q * 8);
#pragma unroll
        for (int mt = 0; mt < 8; ++mt) acc[mt] = (f32x4){0.f, 0.f, 0.f, 0.f};
#pragma unroll
        for (int mt = 0; mt < 8; ++mt) {
#pragma unroll
            for (int ks = 0; ks < 2; ++ks) {
                bf16x8 bb = *(const bf16x8*)(Xal + (mt * 16 + n) * 72 + ks * 32 + q * 8);
                acc[mt] = __builtin_amdgcn_mfma_f32_16x16x32_bf16(a1[ks], bb, acc[mt], 0, 0, 0);
            }
        }
        // epilogue: +b1, relu, write h[m][d] (4 consecutive d per lane -> 8B packs)
        int dbase = wv * 16 + q * 4;
        float bv0 = ldsB1[dbase + 0], bv1 = ldsB1[dbase + 1];
        float bv2 = ldsB1[dbase + 2], bv3 = ldsB1[dbase + 3];
#pragma unroll
        for (int mt = 0; mt < 8; ++mt) {
            int m = mt * 16 + n;
            bf16x4 pk;
            pk[0] = (__bf16)fmaxf(acc[mt][0] + bv0, 0.f);
            pk[1] = (__bf16)fmaxf(acc[mt][1] + bv1, 0.f);
            pk[2] = (__bf16)fmaxf(acc[mt][2] + bv2, 0.f);
            pk[3] = (__bf16)fmaxf(acc[mt][3] + bv3, 0.f);
            *(bf16x4*)(ldsH + m * 136 + dbase) = pk;
        }
    }
    __syncthreads();

    // ---- phase 2: D[j][k] = sum_d h[j][d] * W2[d][k]  (wave wv owns j-band) ; store ST[k][j] ----
    {
        bf16x8 a2[4];
#pragma unroll
        for (int ks = 0; ks < 4; ++ks)
            a2[ks] = *(const bf16x8*)(ldsH + (wv * 16 + n) * 136 + ks * 32 + q * 8);
#pragma unroll
        for (int kt = 0; kt < 8; ++kt) acc[kt] = (f32x4){0.f, 0.f, 0.f, 0.f};
#pragma unroll
        for (int kt = 0; kt < 8; ++kt) {
#pragma unroll
            for (int ks = 0; ks < 4; ++ks) {
                bf16x8 bb = *(const bf16x8*)(ldsW2 + (kt * 16 + n) * 136 + ks * 32 + q * 8);
                acc[kt] = __builtin_amdgcn_mfma_f32_16x16x32_bf16(a2[ks], bb, acc[kt], 0, 0, 0);
            }
        }
        int jbase = wv * 16 + q * 4;
#pragma unroll
        for (int kt = 0; kt < 8; ++kt) {
            int k = kt * 16 + n;
            float bv = ldsB2[k];
            bf16x4 pk;
            pk[0] = (__bf16)(acc[kt][0] + bv);
            pk[1] = (__bf16)(acc[kt][1] + bv);
            pk[2] = (__bf16)(acc[kt][2] + bv);
            pk[3] = (__bf16)(acc[kt][3] + bv);
            *(bf16x4*)(Sl + k * 136 + jbase) = pk;   // Sl aliases Xal/W1Tl: dead after phase 1 barrier
        }
    }
    __syncthreads();

    // ---- phase 3: out[i][k] = sum_j Amain[i][j] * S[j][k]  (wave wv owns i-band) ----
    {
        bf16x8 a3[4];
#pragma unroll
        for (int ks = 0; ks < 4; ++ks) {
            f32x4 lo = apre[2 * ks], hi = apre[2 * ks + 1];
            bf16x8 v;
            v[0] = (__bf16)lo[0]; v[1] = (__bf16)lo[1]; v[2] = (__bf16)lo[2]; v[3] = (__bf16)lo[3];
            v[4] = (__bf16)hi[0]; v[5] = (__bf16)hi[1]; v[6] = (__bf16)hi[2]; v[7] = (__bf16)hi[3];
            a3[ks] = v;
        }
#pragma unroll
        for (int kt = 0; kt < 8; ++kt) acc[kt] = (f32x4){0.f, 0.f, 0.f, 0.f};
#pragma unroll
        for (int kt = 0; kt < 8; ++kt) {
#pragma unroll
            for (int ks = 0; ks < 4; ++ks) {
                bf16x8 bb = *(const bf16x8*)(Sl + (kt * 16 + n) * 136 + ks * 32 + q * 8);
                acc[kt] = __builtin_amdgcn_mfma_f32_16x16x32_bf16(a3[ks], bb, acc[kt], 0, 0, 0);
            }
        }
        float* orow = out + (size_t)t * MM * MM;
        int ibase = wv * 16 + q * 4;
#pragma unroll
        for (int kt = 0; kt < 8; ++kt) {
            int k = kt * 16 + n;
#pragma unroll
            for (int r = 0; r < 4; ++r)
                orow[(size_t)(ibase + r) * MM + k] = acc[kt][r];  // 16 lanes cover a full 64B segment
        }
    }
}

extern "C" void kernel_launch(void* const* d_in, const int* in_sizes, int n_in,
                              void* d_out, int out_size, void* d_ws, size_t ws_size,
                              hipStream_t stream) {
    const float* xm = (const float*)d_in[0];
    const float* xa = (const float*)d_in[1];
    const float* W1 = (const float*)d_in[2];
    const float* b1 = (const float*)d_in[3];
    const float* W2 = (const float*)d_in[4];
    const float* b2 = (const float*)d_in[5];
    float* out = (float*)d_out;
    slam_fused<<<dim3(TT), dim3(512), 0, stream>>>(xm, xa, W1, b1, W2, b2, out);
}